// Round 4
// baseline (430.347 us; speedup 1.0000x reference)
//
#include <hip/hip_runtime.h>
#include <math.h>

// ---------------------------------------------------------------------------
// AttnBlock: per-edge radial-MLP attention logits + segment softmax over dst.
//
// R4 structure (3 stream ops):
//   memset ssum[N]=0 (double)
//   K1 edge:  dot[e] -> d_out (fp32), atomicAdd ssum[v[e]] += exp_wide(dot)
//   K2 norm:  d_out[e] = (float)( exp_wide(dot) / ssum[v[e]] )
//
// exp_wide: fp32 exp2 + bit-built 2^k scaling into double — same range
// semantics as f64 exp (R3-verified necessary: fp32 exp overflowed) at ~1/4
// the VALU cost.
//
// EPT=2: each thread computes 2 consecutive edges so every scalar weight
// load (s_load, ~2460 floats streamed through SGPRs) feeds 2x the pk_fma
// work, and independent memory chains double latency hiding. R3 showed
// VALU 43% / HBM 22% / occ 41% -> latency-bound, not pipe-bound.
// ---------------------------------------------------------------------------

#define TPB 256

typedef float f2 __attribute__((ext_vector_type(2)));
typedef int i2 __attribute__((ext_vector_type(2)));

static __device__ __forceinline__ f2 fma2(f2 a, f2 b, f2 c) {
    return __builtin_elementwise_fma(a, b, c);
}
static __device__ __forceinline__ f2 splat(float x) {
    f2 r;
    r.x = x;
    r.y = x;
    return r;
}
static __device__ __forceinline__ float get16(const f2* h, int c) {
    return (c & 1) ? h[c >> 1].y : h[c >> 1].x;
}

// exp(d) with f64-exp range semantics: result = 2^(d*log2e) as double.
// Valid (identical to f64 exp up to ~1e-5 rel) for |d| <= 1400; clamp
// beyond (exp(-1400)==0, exp(+1400)==inf in double either way).
static __device__ __forceinline__ double exp_wide(float d) {
    d = fminf(fmaxf(d, -1400.f), 1400.f);
    const float t = d * 1.44269504088896340736f;  // log2(e)
    const float k = rintf(t);
    const float p = exp2f(t - k);  // v_exp_f32, frac in [-0.5,0.5]
    const int ik = (int)k;         // |ik| <= 2020
    const int k1 = ik >> 1;
    const int k2 = ik - k1;        // k1+k2=ik, each in [-1010,1010]
    const double s1 = __hiloint2double((k1 + 1023) << 20, 0);  // 2^k1
    const double s2 = __hiloint2double((k2 + 1023) << 20, 0);  // 2^k2
    return ((double)p * s1) * s2;
}

// LayerNorm(16) + ReLU over 2 edges' h[8] (packed pairs); weight loads CSE'd.
static __device__ __forceinline__ void ln_relu16_2(f2 h[2][8],
                                                   const float* __restrict__ g,
                                                   const float* __restrict__ be) {
    const f2* g2 = (const f2*)g;
    const f2* be2 = (const f2*)be;
#pragma unroll
    for (int e = 0; e < 2; ++e) {
        f2 s = h[e][0] + h[e][1] + h[e][2] + h[e][3] + h[e][4] + h[e][5] +
               h[e][6] + h[e][7];
        const float mu = (s.x + s.y) * 0.0625f;
        const f2 mu2 = splat(mu);
        f2 vs = splat(0.f);
#pragma unroll
        for (int i = 0; i < 8; ++i) {
            f2 dd = h[e][i] - mu2;
            vs = fma2(dd, dd, vs);
        }
        const float var = (vs.x + vs.y) * 0.0625f;
        const f2 r2 = splat(rsqrtf(var + 1e-5f));
        const f2 zero = splat(0.f);
#pragma unroll
        for (int i = 0; i < 8; ++i) {
            f2 tt = (h[e][i] - mu2) * r2;
            h[e][i] = __builtin_elementwise_max(fma2(tt, g2[i], be2[i]), zero);
        }
    }
}

// layers 1..2 for 2 edges: vec(3) -> 16 -> LN/relu -> 16 -> LN/relu
static __device__ __forceinline__ void radial_h2_2(
    const float* v0, const float* v1, const float* v2,
    const float* __restrict__ W1, const float* __restrict__ b1,
    const float* __restrict__ g1, const float* __restrict__ be1,
    const float* __restrict__ W2, const float* __restrict__ b2,
    const float* __restrict__ g2, const float* __restrict__ be2,
    f2 h2[2][8]) {
    const f2* W1r0 = (const f2*)W1;
    const f2* W1r1 = (const f2*)(W1 + 16);
    const f2* W1r2 = (const f2*)(W1 + 32);
    const f2* b1v = (const f2*)b1;
    f2 h[2][8];
#pragma unroll
    for (int j = 0; j < 8; ++j) {
        const f2 w0 = W1r0[j], w1 = W1r1[j], w2 = W1r2[j], bb = b1v[j];
#pragma unroll
        for (int e = 0; e < 2; ++e)
            h[e][j] = fma2(splat(v0[e]), w0,
                           fma2(splat(v1[e]), w1, fma2(splat(v2[e]), w2, bb)));
    }
    ln_relu16_2(h, g1, be1);

    const f2* b2v = (const f2*)b2;
#pragma unroll
    for (int j = 0; j < 8; ++j) {
        h2[0][j] = b2v[j];
        h2[1][j] = b2v[j];
    }
#pragma unroll
    for (int c = 0; c < 16; ++c) {
        const f2 hc0 = splat(get16(h[0], c));
        const f2 hc1 = splat(get16(h[1], c));
        const f2* row = (const f2*)(W2 + c * 16);
#pragma unroll
        for (int j = 0; j < 8; ++j) {
            const f2 w = row[j];
            h2[0][j] = fma2(hc0, w, h2[0][j]);
            h2[1][j] = fma2(hc1, w, h2[1][j]);
        }
    }
    ln_relu16_2(h2, g2, be2);
}

// layer3 (OUT=4) for 2 edges: p0[e]={R0,R1}, p1[e]={R2,R3}
static __device__ __forceinline__ void layer3_4_2(const f2 h2[2][8],
                                                  const float* __restrict__ W3,
                                                  const float* __restrict__ b3,
                                                  f2* p0, f2* p1) {
    p0[0] = *(const f2*)(b3);
    p1[0] = *(const f2*)(b3 + 2);
    p0[1] = p0[0];
    p1[1] = p1[0];
#pragma unroll
    for (int c = 0; c < 16; ++c) {
        const f2 wa = *(const f2*)(W3 + c * 4);
        const f2 wb = *(const f2*)(W3 + c * 4 + 2);
#pragma unroll
        for (int e = 0; e < 2; ++e) {
            const f2 hc = splat(get16(h2[e], c));
            p0[e] = fma2(hc, wa, p0[e]);
            p1[e] = fma2(hc, wb, p1[e]);
        }
    }
}

__global__ __launch_bounds__(TPB, 3) void edge_kernel(
    const float* __restrict__ f0, const float* __restrict__ f1,
    const float* __restrict__ dist, const int* __restrict__ u,
    const int* __restrict__ v, const float* __restrict__ wq,
    const float* __restrict__ wj00, const float* __restrict__ wj01,
    const float* __restrict__ wj10, const float* __restrict__ wj11,
    const float* __restrict__ rW1, const float* __restrict__ rb1,
    const float* __restrict__ g1, const float* __restrict__ be1,
    const float* __restrict__ rW2, const float* __restrict__ rb2,
    const float* __restrict__ g2, const float* __restrict__ be2,
    const float* __restrict__ W3_00, const float* __restrict__ b3_00,
    const float* __restrict__ W3_01, const float* __restrict__ b3_01,
    const float* __restrict__ W3_10, const float* __restrict__ b3_10,
    const float* __restrict__ W3_11, const float* __restrict__ b3_11,
    float* __restrict__ out, double* __restrict__ ssum, int E) {
    const int t = blockIdx.x * blockDim.x + threadIdx.x;
    const int e0 = t * 2;
    if (e0 >= E) return;
    const bool has1 = (e0 + 1) < E;

    int ea[2], va_[2];
    float dd[2], w00[2];
    if (has1) {
        const i2 uu2 = __builtin_nontemporal_load((const i2*)u + t);
        const i2 vv2 = __builtin_nontemporal_load((const i2*)v + t);
        const f2 dd2 = __builtin_nontemporal_load((const f2*)dist + t);
        const f2 w002 = __builtin_nontemporal_load((const f2*)wj00 + t);
        ea[0] = uu2.x;
        ea[1] = uu2.y;
        va_[0] = vv2.x;
        va_[1] = vv2.y;
        dd[0] = dd2.x;
        dd[1] = dd2.y;
        w00[0] = w002.x;
        w00[1] = w002.y;
    } else {
        ea[0] = ea[1] = u[e0];
        va_[0] = va_[1] = v[e0];
        dd[0] = dd[1] = dist[e0];
        w00[0] = w00[1] = wj00[e0];
    }
    const int eidx[2] = {e0, has1 ? e0 + 1 : e0};

    float f0u0[2], f0u1[2], f0v0[2], f0v1[2];
    float f1v[2][2][3];
#pragma unroll
    for (int e = 0; e < 2; ++e) {
        const int uu = ea[e];
        const int vv = va_[e];
        f0u0[e] = f0[uu * 2 + 0];
        f0u1[e] = f0[uu * 2 + 1];
        f0v0[e] = f0[vv * 2 + 0];
        f0v1[e] = f0[vv * 2 + 1];
#pragma unroll
        for (int i = 0; i < 2; ++i)
#pragma unroll
            for (int m = 0; m < 3; ++m) f1v[e][i][m] = f1[vv * 6 + i * 3 + m];
    }

    float vec0[2], vec1[2], vec2[2];
#pragma unroll
    for (int e = 0; e < 2; ++e) {
        vec0[e] = f0u0[e] * f0v0[e];
        vec1[e] = f0u1[e] * f0v1[e];
        vec2[e] = dd[e];
    }

    float acc0[2][2] = {{0.f, 0.f}, {0.f, 0.f}};
    float acc1[2][2][3] = {{{0.f}}, {{0.f}}};

    // ---- MLP i=0: (l=0,k=0) ----
    {
        f2 h2[2][8];
        radial_h2_2(vec0, vec1, vec2, rW1 + 0 * 48, rb1 + 0 * 16, g1 + 0 * 16,
                    be1 + 0 * 16, rW2 + 0 * 256, rb2 + 0 * 16, g2 + 0 * 16,
                    be2 + 0 * 16, h2);
        f2 p0[2], p1[2];
        layer3_4_2(h2, W3_00, b3_00, p0, p1);
#pragma unroll
        for (int e = 0; e < 2; ++e) {
            acc0[e][0] += w00[e] * (p0[e].x * f0v0[e] + p0[e].y * f0v1[e]);
            acc0[e][1] += w00[e] * (p1[e].x * f0v0[e] + p1[e].y * f0v1[e]);
        }
    }
    // ---- MLP i=1: (l=0,k=1) ----
    {
        f2 h2[2][8];
        radial_h2_2(vec0, vec1, vec2, rW1 + 1 * 48, rb1 + 1 * 16, g1 + 1 * 16,
                    be1 + 1 * 16, rW2 + 1 * 256, rb2 + 1 * 16, g2 + 1 * 16,
                    be2 + 1 * 16, h2);
        f2 p0[2], p1[2];
        layer3_4_2(h2, W3_01, b3_01, p0, p1);
#pragma unroll
        for (int e = 0; e < 2; ++e) {
            const float w0 = wj01[eidx[e] * 3 + 0];
            const float w1 = wj01[eidx[e] * 3 + 1];
            const float w2 = wj01[eidx[e] * 3 + 2];
            const float s0 =
                w0 * f1v[e][0][0] + w1 * f1v[e][0][1] + w2 * f1v[e][0][2];
            const float s1 =
                w0 * f1v[e][1][0] + w1 * f1v[e][1][1] + w2 * f1v[e][1][2];
            acc0[e][0] += p0[e].x * s0 + p0[e].y * s1;
            acc0[e][1] += p1[e].x * s0 + p1[e].y * s1;
        }
    }
    // ---- MLP i=2: (l=1,k=0) ----
    {
        f2 h2[2][8];
        radial_h2_2(vec0, vec1, vec2, rW1 + 2 * 48, rb1 + 2 * 16, g1 + 2 * 16,
                    be1 + 2 * 16, rW2 + 2 * 256, rb2 + 2 * 16, g2 + 2 * 16,
                    be2 + 2 * 16, h2);
        f2 p0[2], p1[2];
        layer3_4_2(h2, W3_10, b3_10, p0, p1);
#pragma unroll
        for (int e = 0; e < 2; ++e) {
            const float t0 = p0[e].x * f0v0[e] + p0[e].y * f0v1[e];
            const float t1 = p1[e].x * f0v0[e] + p1[e].y * f0v1[e];
#pragma unroll
            for (int m = 0; m < 3; ++m) {
                const float w = wj10[eidx[e] * 3 + m];
                acc1[e][0][m] += w * t0;
                acc1[e][1][m] += w * t1;
            }
        }
    }
    // ---- MLP i=3: (l=1,k=1): layer3 per j-row, consumed immediately ----
    {
        f2 h2[2][8];
        radial_h2_2(vec0, vec1, vec2, rW1 + 3 * 48, rb1 + 3 * 16, g1 + 3 * 16,
                    be1 + 3 * 16, rW2 + 3 * 256, rb2 + 3 * 16, g2 + 3 * 16,
                    be2 + 3 * 16, h2);
#pragma unroll
        for (int j = 0; j < 3; ++j) {
            f2 p0[2], p1[2];
            p0[0] = *(const f2*)(b3_11 + j * 4);
            p1[0] = *(const f2*)(b3_11 + j * 4 + 2);
            p0[1] = p0[0];
            p1[1] = p1[0];
#pragma unroll
            for (int c = 0; c < 16; ++c) {
                const f2 wa = *(const f2*)(W3_11 + c * 12 + j * 4);
                const f2 wb = *(const f2*)(W3_11 + c * 12 + j * 4 + 2);
#pragma unroll
                for (int e = 0; e < 2; ++e) {
                    const f2 hc = splat(get16(h2[e], c));
                    p0[e] = fma2(hc, wa, p0[e]);
                    p1[e] = fma2(hc, wb, p1[e]);
                }
            }
#pragma unroll
            for (int e = 0; e < 2; ++e) {
#pragma unroll
                for (int m = 0; m < 3; ++m) {
                    const float w0 = wj11[eidx[e] * 27 + j * 9 + m * 3 + 0];
                    const float w1 = wj11[eidx[e] * 27 + j * 9 + m * 3 + 1];
                    const float w2 = wj11[eidx[e] * 27 + j * 9 + m * 3 + 2];
                    const float B0 = w0 * f1v[e][0][0] + w1 * f1v[e][0][1] +
                                     w2 * f1v[e][0][2];
                    const float B1 = w0 * f1v[e][1][0] + w1 * f1v[e][1][1] +
                                     w2 * f1v[e][1][2];
                    acc1[e][0][m] += p0[e].x * B0 + p0[e].y * B1;
                    acc1[e][1][m] += p1[e].x * B0 + p1[e].y * B1;
                }
            }
        }
    }

    // ---- q[v] . k_feat ----  wq[d][o][i] = wq[d*4+o*2+i]
    float dotv[2];
#pragma unroll
    for (int e = 0; e < 2; ++e) {
        float dot = 0.f;
        const float q00 = wq[0] * f0v0[e] + wq[1] * f0v1[e];
        const float q01 = wq[2] * f0v0[e] + wq[3] * f0v1[e];
        dot += q00 * acc0[e][0] + q01 * acc0[e][1];
#pragma unroll
        for (int m = 0; m < 3; ++m) {
            const float q1m0 = wq[4] * f1v[e][0][m] + wq[5] * f1v[e][1][m];
            const float q1m1 = wq[6] * f1v[e][0][m] + wq[7] * f1v[e][1][m];
            dot += q1m0 * acc1[e][0][m] + q1m1 * acc1[e][1][m];
        }
        dotv[e] = dot;
    }

    if (has1) {
        f2 st;
        st.x = dotv[0];
        st.y = dotv[1];
        __builtin_nontemporal_store(st, (f2*)out + t);
    } else {
        out[e0] = dotv[0];
    }
    atomicAdd(&ssum[va_[0]], exp_wide(dotv[0]));
    if (has1) atomicAdd(&ssum[va_[1]], exp_wide(dotv[1]));
}

__global__ void norm_kernel(float* __restrict__ out, const int* __restrict__ v,
                            const double* __restrict__ ssum, int E) {
    const int t = blockIdx.x * blockDim.x + threadIdx.x;
    const int e0 = t * 2;
    if (e0 >= E) return;
    if (e0 + 1 < E) {
        const f2 dv = __builtin_nontemporal_load((const f2*)out + t);
        const i2 vv = __builtin_nontemporal_load((const i2*)v + t);
        const double s0 = ssum[vv.x];
        const double s1 = ssum[vv.y];
        f2 r;
        r.x = (float)(exp_wide(dv.x) / s0);
        r.y = (float)(exp_wide(dv.y) / s1);
        __builtin_nontemporal_store(r, (f2*)out + t);
    } else {
        out[e0] = (float)(exp_wide(out[e0]) / ssum[v[e0]]);
    }
}

extern "C" void kernel_launch(void* const* d_in, const int* in_sizes, int n_in,
                              void* d_out, int out_size, void* d_ws,
                              size_t ws_size, hipStream_t stream) {
    const float* f0 = (const float*)d_in[0];
    const float* f1 = (const float*)d_in[1];
    const float* dist = (const float*)d_in[2];
    const int* u = (const int*)d_in[3];
    const int* v = (const int*)d_in[4];
    const float* wq = (const float*)d_in[5];
    const float* wj00 = (const float*)d_in[6];
    const float* wj01 = (const float*)d_in[7];
    const float* wj10 = (const float*)d_in[8];
    const float* wj11 = (const float*)d_in[9];
    const float* rW1 = (const float*)d_in[10];
    const float* rb1 = (const float*)d_in[11];
    const float* g1 = (const float*)d_in[12];
    const float* be1 = (const float*)d_in[13];
    const float* rW2 = (const float*)d_in[14];
    const float* rb2 = (const float*)d_in[15];
    const float* g2 = (const float*)d_in[16];
    const float* be2 = (const float*)d_in[17];
    const float* W3_00 = (const float*)d_in[18];
    const float* b3_00 = (const float*)d_in[19];
    const float* W3_01 = (const float*)d_in[20];
    const float* b3_01 = (const float*)d_in[21];
    const float* W3_10 = (const float*)d_in[22];
    const float* b3_10 = (const float*)d_in[23];
    const float* W3_11 = (const float*)d_in[24];
    const float* b3_11 = (const float*)d_in[25];

    const int N = in_sizes[0] / 2;  // f0 is [N,2,1]
    const int E = in_sizes[2];      // dist is [E]

    double* ssum = (double*)d_ws;
    float* out = (float*)d_out;

    const int pairs = (E + 1) / 2;
    const int gp = (pairs + TPB - 1) / TPB;

    hipMemsetAsync(ssum, 0, (size_t)N * sizeof(double), stream);
    edge_kernel<<<gp, TPB, 0, stream>>>(
        f0, f1, dist, u, v, wq, wj00, wj01, wj10, wj11, rW1, rb1, g1, be1, rW2,
        rb2, g2, be2, W3_00, b3_00, W3_01, b3_01, W3_10, b3_10, W3_11, b3_11,
        out, ssum, E);
    norm_kernel<<<gp, TPB, 0, stream>>>(out, v, ssum, E);
}